// Round 4
// baseline (492.771 us; speedup 1.0000x reference)
//
#include <hip/hip_runtime.h>
#include <hip/hip_bf16.h>
#include <cstdint>

#define T_TOK 4096
#define DMODEL 1024
#define HDIM 2048

typedef short bf16x8 __attribute__((ext_vector_type(8)));
typedef float f32x4 __attribute__((ext_vector_type(4)));
typedef uint32_t u32x4 __attribute__((ext_vector_type(4)));

#define WAITVM(N) asm volatile("s_waitcnt vmcnt(" #N ")" ::: "memory")
#define BAR() asm volatile("s_barrier" ::: "memory")

__device__ __forceinline__ uint32_t cvt_pk_bf16(float lo, float hi) {
  uint32_t d;
  asm("v_cvt_pk_bf16_f32 %0, %1, %2" : "=v"(d) : "v"(lo), "v"(hi));
  return d;
}
__device__ __forceinline__ unsigned short f2bf(float f) {
  uint32_t d;
  asm("v_cvt_pk_bf16_f32 %0, %1, %1" : "=v"(d) : "v"(f));
  return (unsigned short)d;
}
__device__ __forceinline__ float gelu_erf(float v) {
  return 0.5f * v * (1.0f + erff(v * 0.70710678118654752f));
}
__device__ __forceinline__ void gload16(const void* g, void* lds) {
  __builtin_amdgcn_global_load_lds((const __attribute__((address_space(1))) void*)g,
                                   (__attribute__((address_space(3))) void*)lds, 16, 0, 0);
}
__device__ __forceinline__ u32x4 pk8(const float* s) {
  float4 v0 = ((const float4*)s)[0], v1 = ((const float4*)s)[1];
  u32x4 p = {cvt_pk_bf16(v0.x, v0.y), cvt_pk_bf16(v0.z, v0.w),
             cvt_pk_bf16(v1.x, v1.y), cvt_pk_bf16(v1.z, v1.w)};
  return p;
}

// ---------------- merged weight conversion (fragment-major bf16) ----------------
// wu/wg per expert: [h16:128][d32:32][lane:64][8]   wd per expert: [d16:64][h32:64][lane:64][8]
__global__ __launch_bounds__(256) void convert_w(
    const float* __restrict__ w1, const float* __restrict__ w3,
    const float* __restrict__ w1s, const float* __restrict__ w3s,
    const float* __restrict__ w2, const float* __restrict__ w2s,
    short* __restrict__ wu, short* __restrict__ wg, short* __restrict__ wd) {
  int bid = blockIdx.x;
  if (bid < 9216) {
    int id = bid * 256 + threadIdx.x;
    int e = id >> 18, rem = id & 262143;
    int h16 = rem >> 11, d32 = (rem >> 6) & 31, ln = rem & 63;
    size_t so = (size_t)(h16 * 16 + (ln & 15)) * DMODEL + d32 * 32 + (ln >> 4) * 8;
    const float* s1 = (e < 8) ? w1 + (size_t)e * 2097152 + so : w1s + so;
    const float* s3 = (e < 8) ? w3 + (size_t)e * 2097152 + so : w3s + so;
    *(u32x4*)(wu + (size_t)id * 8) = pk8(s1);
    *(u32x4*)(wg + (size_t)id * 8) = pk8(s3);
  } else {
    int id = (bid - 9216) * 256 + threadIdx.x;
    int e = id >> 18, rem = id & 262143;
    int d16 = rem >> 12, h32 = (rem >> 6) & 63, ln = rem & 63;
    size_t so = (size_t)(d16 * 16 + (ln & 15)) * HDIM + h32 * 32 + (ln >> 4) * 8;
    const float* s2 = (e < 8) ? w2 + (size_t)e * 2097152 + so : w2s + so;
    *(u32x4*)(wd + (size_t)id * 8) = pk8(s2);
  }
}

// ---------------- router: one wave per token; also emits xb (bf16 x) ----------------
__global__ __launch_bounds__(256) void router_kernel(
    const float* __restrict__ x, const float* __restrict__ Wr,
    int* __restrict__ cursor, int* __restrict__ cnt1,
    float* __restrict__ psum, int* __restrict__ perm, float* __restrict__ pw,
    short* __restrict__ xb) {
  __shared__ float4 sW[8 * 256];
  __shared__ float sP[8];
  int tid = threadIdx.x;
  const float4* W4 = (const float4*)Wr;
  for (int i = tid; i < 2048; i += 256) sW[i] = W4[i];
  if (tid < 8) sP[tid] = 0.f;
  __syncthreads();

  int lane = tid & 63, wid = tid >> 6;
  int t = blockIdx.x * 4 + wid;
  float acc[8] = {0.f, 0.f, 0.f, 0.f, 0.f, 0.f, 0.f, 0.f};
  const float4* x4 = (const float4*)(x + (size_t)t * DMODEL);
#pragma unroll
  for (int it = 0; it < 4; ++it) {
    float4 xv = x4[it * 64 + lane];
    uint2 pk = {cvt_pk_bf16(xv.x, xv.y), cvt_pk_bf16(xv.z, xv.w)};
    *(uint2*)(xb + (size_t)t * DMODEL + it * 256 + lane * 4) = pk;
#pragma unroll
    for (int e = 0; e < 8; ++e) {
      float4 wv = sW[e * 256 + it * 64 + lane];
      acc[e] += xv.x * wv.x + xv.y * wv.y + xv.z * wv.z + xv.w * wv.w;
    }
  }
#pragma unroll
  for (int e = 0; e < 8; ++e)
    for (int off = 32; off; off >>= 1) acc[e] += __shfl_xor(acc[e], off);

  float mx = acc[0];
#pragma unroll
  for (int e = 1; e < 8; ++e) mx = fmaxf(mx, acc[e]);
  float ex[8], s = 0.f;
#pragma unroll
  for (int e = 0; e < 8; ++e) { ex[e] = expf(acc[e] - mx); s += ex[e]; }
  float inv = 1.f / s;
  int e0 = 0;
#pragma unroll
  for (int e = 1; e < 8; ++e) if (acc[e] > acc[e0]) e0 = e;
  int e1 = (e0 == 0) ? 1 : 0;
#pragma unroll
  for (int e = 0; e < 8; ++e) if (e != e0 && acc[e] > acc[e1]) e1 = e;

  if (lane == 0) {
#pragma unroll
    for (int e = 0; e < 8; ++e) atomicAdd(&sP[e], ex[e] * inv);
    atomicAdd(&cnt1[e0], 1);
    int s0 = atomicAdd(&cursor[e0], 1);
    perm[e0 * 4096 + s0] = t; pw[e0 * 4096 + s0] = ex[e0] * inv;
    int s1 = atomicAdd(&cursor[e1], 1);
    perm[e1 * 4096 + s1] = t; pw[e1 * 4096 + s1] = ex[e1] * inv;
  }
  __syncthreads();
  if (tid < 8) atomicAdd(&psum[tid], sP[tid]);
}

// ---------------- finalize: padded bases + aux loss ----------------
__global__ void finalize_kernel(const int* __restrict__ cursor,
                                const int* __restrict__ cnt1,
                                const float* __restrict__ psum,
                                int* __restrict__ base, float* __restrict__ aux_out) {
  if (threadIdx.x == 0) {
    int b = 0;
    for (int e = 0; e < 8; ++e) { base[e] = b; b += ((cursor[e] + 127) >> 7) << 7; }
    base[8] = b;
    float aux = 0.f;
    for (int e = 0; e < 8; ++e)
      aux += ((float)cnt1[e] * (1.f / T_TOK)) * (psum[e] * (1.f / T_TOK));
    aux_out[0] = 0.01f * 8.f * aux;
  }
}

// ---- fused up+gate GEMM: 3-deep pipeline, counted vmcnt, raw barriers, BK=32 ----
__global__ __launch_bounds__(256, 2) void gemm_upgate(
    const short* __restrict__ xb,
    const short* __restrict__ wu, const short* __restrict__ wg,
    const int* __restrict__ cursor, const int* __restrict__ base,
    const int* __restrict__ perm, unsigned short* __restrict__ hbuf) {
  int e = blockIdx.z, mt = blockIdx.y, nt = blockIdx.x;
  int cnt = (e < 8) ? cursor[e] : 4096;
  if (mt * 128 >= cnt) return;
  int hb = base[e];
  const short* wuE = wu + (size_t)e * 2097152;
  const short* wgE = wg + (size_t)e * 2097152;

  __shared__ short As[3][4096], Bs1[3][4096], Bs3[3][4096];

  int tid = threadIdx.x, lane = tid & 63, wid = tid >> 6;
  int fr = lane & 15, ko8 = (lane >> 4) * 8;
  int wr = wid >> 1, wc = wid & 1;

  size_t aOff[2], bOff[2];
#pragma unroll
  for (int s = 0; s < 2; ++s) {
    int g = s * 4 + wid;
    int slot = mt * 128 + g * 16 + fr;
    int tok = (e == 8) ? slot : ((slot < cnt) ? perm[e * 4096 + slot] : 0);
    aOff[s] = (size_t)tok * DMODEL + ko8;
    bOff[s] = ((size_t)(nt * 8 + g) * 32 * 64 + lane) * 8;
  }

  f32x4 acc1[4][4] = {}, acc3[4][4] = {};

  auto stage = [&](int buf, int it) {   // 6 vmem ops per thread
#pragma unroll
    for (int s = 0; s < 2; ++s) {
      int g = s * 4 + wid;
      gload16(xb + aOff[s] + it * 32, &As[buf][g * 512 + lane * 8]);
      size_t cb = bOff[s] + (size_t)it * 512;
      gload16(wuE + cb, &Bs1[buf][g * 512 + lane * 8]);
      gload16(wgE + cb, &Bs3[buf][g * 512 + lane * 8]);
    }
  };
  auto compute = [&](int buf) {
    bf16x8 af[4], b1f[4], b3f[4];
#pragma unroll
    for (int m = 0; m < 4; ++m)
      af[m] = *(const bf16x8*)&As[buf][(wr * 4 + m) * 512 + lane * 8];
#pragma unroll
    for (int n = 0; n < 4; ++n) {
      b1f[n] = *(const bf16x8*)&Bs1[buf][(wc * 4 + n) * 512 + lane * 8];
      b3f[n] = *(const bf16x8*)&Bs3[buf][(wc * 4 + n) * 512 + lane * 8];
    }
    __builtin_amdgcn_s_setprio(1);
#pragma unroll
    for (int m = 0; m < 4; ++m)
#pragma unroll
      for (int n = 0; n < 4; ++n) {
        acc1[m][n] = __builtin_amdgcn_mfma_f32_16x16x32_bf16(af[m], b1f[n], acc1[m][n], 0, 0, 0);
        acc3[m][n] = __builtin_amdgcn_mfma_f32_16x16x32_bf16(af[m], b3f[n], acc3[m][n], 0, 0, 0);
      }
    __builtin_amdgcn_s_setprio(0);
  };

  stage(0, 0);
  stage(1, 1);
  int cur = 0, pf = 2;
#pragma unroll 1
  for (int it = 0; it < 30; ++it) {
    stage(pf, it + 2);
    WAITVM(12);            // current tile's 6 loads done; 12 newer stay in flight
    BAR();
    compute(cur);
    BAR();
    pf = cur; cur = (cur == 2) ? 0 : cur + 1;
  }
  WAITVM(6); BAR(); compute(cur); BAR();
  cur = (cur == 2) ? 0 : cur + 1;
  WAITVM(0); BAR(); compute(cur);

  int q = lane >> 4;
#pragma unroll
  for (int m = 0; m < 4; ++m) {
#pragma unroll
    for (int n = 0; n < 4; ++n) {
      int col = nt * 128 + wc * 64 + n * 16 + fr;
      f32x4 u = acc1[m][n], g = acc3[m][n];
#pragma unroll
      for (int j = 0; j < 4; ++j) {
        int sl = mt * 128 + wr * 64 + m * 16 + q * 4 + j;
        float hv = (sl < cnt) ? gelu_erf(u[j]) * g[j] : 0.f;
        hbuf[(size_t)(hb + sl) * HDIM + col] = f2bf(hv);
      }
    }
  }
}

// ---- down GEMM: 3-deep pipeline, counted vmcnt, weighted scatter ----
__global__ __launch_bounds__(256, 3) void gemm_down(
    const unsigned short* __restrict__ hbuf,
    const short* __restrict__ wd,
    const int* __restrict__ cursor, const int* __restrict__ base,
    const int* __restrict__ perm, const float* __restrict__ pw,
    float* __restrict__ out) {
  int e = blockIdx.z, mt = blockIdx.y, nt = blockIdx.x;
  int cnt = (e < 8) ? cursor[e] : 4096;
  if (mt * 128 >= cnt) return;
  int hb = base[e];
  const short* wdE = wd + (size_t)e * 2097152;

  __shared__ short As[3][4096], Bs[3][4096];

  int tid = threadIdx.x, lane = tid & 63, wid = tid >> 6;
  int fr = lane & 15, ko8 = (lane >> 4) * 8;
  int wr = wid >> 1, wc = wid & 1;

  size_t aOff[2], bOff[2];
#pragma unroll
  for (int s = 0; s < 2; ++s) {
    int g = s * 4 + wid;
    aOff[s] = (size_t)(hb + mt * 128 + g * 16 + fr) * HDIM + ko8;
    bOff[s] = ((size_t)(nt * 8 + g) * 64 * 64 + lane) * 8;
  }

  f32x4 acc[4][4] = {};

  auto stage = [&](int buf, int it) {   // 4 vmem ops per thread
#pragma unroll
    for (int s = 0; s < 2; ++s) {
      int g = s * 4 + wid;
      gload16(hbuf + aOff[s] + it * 32, &As[buf][g * 512 + lane * 8]);
      gload16(wdE + bOff[s] + (size_t)it * 512, &Bs[buf][g * 512 + lane * 8]);
    }
  };
  auto compute = [&](int buf) {
    bf16x8 af[4], bf[4];
#pragma unroll
    for (int m = 0; m < 4; ++m)
      af[m] = *(const bf16x8*)&As[buf][(wr * 4 + m) * 512 + lane * 8];
#pragma unroll
    for (int n = 0; n < 4; ++n)
      bf[n] = *(const bf16x8*)&Bs[buf][(wc * 4 + n) * 512 + lane * 8];
    __builtin_amdgcn_s_setprio(1);
#pragma unroll
    for (int m = 0; m < 4; ++m)
#pragma unroll
      for (int n = 0; n < 4; ++n)
        acc[m][n] = __builtin_amdgcn_mfma_f32_16x16x32_bf16(af[m], bf[n], acc[m][n], 0, 0, 0);
    __builtin_amdgcn_s_setprio(0);
  };

  stage(0, 0);
  stage(1, 1);
  int cur = 0, pf = 2;
#pragma unroll 1
  for (int it = 0; it < 62; ++it) {
    stage(pf, it + 2);
    WAITVM(8);
    BAR();
    compute(cur);
    BAR();
    pf = cur; cur = (cur == 2) ? 0 : cur + 1;
  }
  WAITVM(4); BAR(); compute(cur); BAR();
  cur = (cur == 2) ? 0 : cur + 1;
  WAITVM(0); BAR(); compute(cur);

  int q = lane >> 4;
#pragma unroll
  for (int m = 0; m < 4; ++m) {
#pragma unroll
    for (int n = 0; n < 4; ++n) {
      int col = nt * 128 + wc * 64 + n * 16 + fr;
      f32x4 a = acc[m][n];
#pragma unroll
      for (int j = 0; j < 4; ++j) {
        int sl = mt * 128 + wr * 64 + m * 16 + q * 4 + j;
        if (sl < cnt) {
          int tok; float p;
          if (e == 8) { tok = sl; p = 1.f; }
          else { tok = perm[e * 4096 + sl]; p = pw[e * 4096 + sl]; }
          atomicAdd(&out[(size_t)tok * DMODEL + col], p * a[j]);
        }
      }
    }
  }
}

extern "C" void kernel_launch(void* const* d_in, const int* in_sizes, int n_in,
                              void* d_out, int out_size, void* d_ws, size_t ws_size,
                              hipStream_t stream) {
  const float* x   = (const float*)d_in[0];
  const float* Wr  = (const float*)d_in[1];
  const float* w1  = (const float*)d_in[2];
  const float* w2  = (const float*)d_in[3];
  const float* w3  = (const float*)d_in[4];
  const float* w1s = (const float*)d_in[5];
  const float* w2s = (const float*)d_in[6];
  const float* w3s = (const float*)d_in[7];
  float* out = (float*)d_out;

  char* ws = (char*)d_ws;
  const size_t HBUF_OFF = 0;                       // 16384*2048 bf16
  const size_t XB_OFF   = 67108864;                // 4096*1024 bf16
  const size_t WU_OFF   = XB_OFF + 8388608;        // 9*2M bf16
  const size_t WG_OFF   = WU_OFF + 37748736;
  const size_t WD_OFF   = WG_OFF + 37748736;
  const size_t PERM_OFF = WD_OFF + 37748736;
  const size_t PW_OFF   = PERM_OFF + 131072;
  const size_t CTRL_OFF = PW_OFF + 131072;

  unsigned short* hbuf = (unsigned short*)(ws + HBUF_OFF);
  short* xb = (short*)(ws + XB_OFF);
  short* wu = (short*)(ws + WU_OFF);
  short* wg = (short*)(ws + WG_OFF);
  short* wd = (short*)(ws + WD_OFF);
  int*   perm   = (int*)(ws + PERM_OFF);
  float* pw     = (float*)(ws + PW_OFF);
  int*   cursor = (int*)(ws + CTRL_OFF);
  int*   cnt1   = (int*)(ws + CTRL_OFF + 64);
  float* psum   = (float*)(ws + CTRL_OFF + 128);
  int*   base   = (int*)(ws + CTRL_OFF + 192);

  hipMemsetAsync(d_out, 0, (size_t)out_size * sizeof(float), stream);
  hipMemsetAsync(ws + CTRL_OFF, 0, 256, stream);

  router_kernel<<<1024, 256, 0, stream>>>(x, Wr, cursor, cnt1, psum, perm, pw, xb);
  finalize_kernel<<<1, 64, 0, stream>>>(cursor, cnt1, psum, base,
                                        out + (size_t)T_TOK * DMODEL);
  convert_w<<<18432, 256, 0, stream>>>(w1, w3, w1s, w3s, w2, w2s, wu, wg, wd);
  gemm_upgate<<<dim3(16, 32, 9), 256, 0, stream>>>(xb, wu, wg, cursor, base, perm, hbuf);
  gemm_down<<<dim3(8, 32, 9), 256, 0, stream>>>(hbuf, wd, cursor, base, perm, pw, out);
}